// Round 12
// baseline (352.540 us; speedup 1.0000x reference)
//
#include <hip/hip_runtime.h>

#define HIDN 1024
#define EXPN 2048
#define SDIM 16
#define DTRN 64
#define BBN  4
#define TTN  2048
#define MMN  (BBN*TTN)        // 8192 rows
#define NCHUNK 64
#define CLEN (TTN/NCHUNK)     // 32
#define KSPL 4                // split-K chunks for k_proj
#define KCH  (EXPN/KSPL)      // 512

typedef unsigned short u16;
typedef __bf16 bf16x8 __attribute__((ext_vector_type(8)));
typedef float f32x4 __attribute__((ext_vector_type(4)));
typedef float f32x2v __attribute__((ext_vector_type(2)));

static __device__ __forceinline__ float b2f(u16 u) {
    union { unsigned int i; float f; } cv; cv.i = ((unsigned int)u) << 16; return cv.f;
}
static __device__ __forceinline__ u16 f2b(float f) {
    union { float f; unsigned int i; } cv; cv.f = f;
    unsigned int x = cv.i;
    return (u16)((x + 0x7fffu + ((x >> 16) & 1u)) >> 16);
}
static __device__ __forceinline__ float fexp2(float x) {
    return __builtin_amdgcn_exp2f(x);
}
static __device__ __forceinline__ float fsilu(float v) {
    return v / (1.f + fexp2(-1.44269504088896f * v));
}
template<int L> static __device__ __forceinline__ void waitcnt_vm() {
    if constexpr (L == 0) asm volatile("s_waitcnt vmcnt(0)" ::: "memory");
    else if constexpr (L == 3) asm volatile("s_waitcnt vmcnt(3)" ::: "memory");
    else if constexpr (L == 4) asm volatile("s_waitcnt vmcnt(4)" ::: "memory");
}

// ------- fused prep: LayerNorm + 3 transposes + cat + a2, ONE launch -------
static __device__ __forceinline__
void tr_tile(const float* __restrict__ W, u16* __restrict__ Wt,
             int K, int N, int bk, int bn, float (*t)[65]) {
    const int r0 = threadIdx.x >> 4, c0 = (threadIdx.x & 15) << 2;
    #pragma unroll
    for (int i = 0; i < 4; ++i) {
        float4 v = *(const float4*)(W + (size_t)(bk + r0 + i * 16) * N + bn + c0);
        t[r0 + i * 16][c0 + 0] = v.x; t[r0 + i * 16][c0 + 1] = v.y;
        t[r0 + i * 16][c0 + 2] = v.z; t[r0 + i * 16][c0 + 3] = v.w;
    }
    __syncthreads();
    #pragma unroll
    for (int i = 0; i < 4; ++i) {
        const int n = r0 + i * 16;
        ushort4 o;
        o.x = f2b(t[c0 + 0][n]); o.y = f2b(t[c0 + 1][n]);
        o.z = f2b(t[c0 + 2][n]); o.w = f2b(t[c0 + 3][n]);
        *(ushort4*)(Wt + (size_t)(bn + n) * K + bk + c0) = o;
    }
}

__global__ __launch_bounds__(256)
void k_prep(const float* __restrict__ x, const float* __restrict__ ln_g,
            const float* __restrict__ ln_b,
            const float* __restrict__ W_in, const float* __restrict__ W_out,
            const float* __restrict__ W_dt, const float* __restrict__ W_del,
            const float* __restrict__ W_B, const float* __restrict__ W_C,
            const float* __restrict__ A_log,
            u16* __restrict__ xn,
            u16* __restrict__ Wt_in, u16* __restrict__ Wt_out,
            u16* __restrict__ Wdt_t, u16* __restrict__ Wcat,
            float* __restrict__ A2) {
    __shared__ float t[64][65];
    __shared__ float as[4], bs[4];
    int blk = blockIdx.x;
    if (blk < MMN) {                         // LayerNorm rows
        const int row = blk, tid = threadIdx.x;
        const float4 xv = ((const float4*)(x + (size_t)row * HIDN))[tid];
        float s  = xv.x + xv.y + xv.z + xv.w;
        float ss = fmaf(xv.x, xv.x, fmaf(xv.y, xv.y, fmaf(xv.z, xv.z, xv.w * xv.w)));
        #pragma unroll
        for (int o = 32; o > 0; o >>= 1) { s += __shfl_down(s, o); ss += __shfl_down(ss, o); }
        const int wid = tid >> 6, lane = tid & 63;
        if (lane == 0) { as[wid] = s; bs[wid] = ss; }
        __syncthreads();
        const float S  = as[0] + as[1] + as[2] + as[3];
        const float SS = bs[0] + bs[1] + bs[2] + bs[3];
        const float mean = S * (1.f / HIDN);
        const float var  = SS * (1.f / HIDN) - mean * mean;
        const float r = rsqrtf(var + 1e-5f);
        const float4 gv = ((const float4*)ln_g)[tid];
        const float4 bv = ((const float4*)ln_b)[tid];
        ushort4 o;
        o.x = f2b((xv.x - mean) * r * gv.x + bv.x);
        o.y = f2b((xv.y - mean) * r * gv.y + bv.y);
        o.z = f2b((xv.z - mean) * r * gv.z + bv.z);
        o.w = f2b((xv.w - mean) * r * gv.w + bv.w);
        ((ushort4*)(xn + (size_t)row * HIDN))[tid] = o;
        return;
    }
    blk -= MMN;
    if (blk < 1024) {
        tr_tile(W_in, Wt_in, HIDN, 2 * EXPN, (blk >> 6) << 6, (blk & 63) << 6, t);
        return;
    }
    blk -= 1024;
    if (blk < 512) {
        tr_tile(W_out, Wt_out, EXPN, HIDN, (blk >> 4) << 6, (blk & 15) << 6, t);
        return;
    }
    blk -= 512;
    if (blk < 32) {
        tr_tile(W_dt, Wdt_t, DTRN, EXPN, 0, blk << 6, t);
        return;
    }
    blk -= 32;
    if (blk < 768) {
        const int i = blk * 256 + threadIdx.x;
        const int n = i >> 11, k = i & 2047;
        float v;
        if (n < 64)      v = W_del[(size_t)k * DTRN + n];
        else if (n < 80) v = W_B[(size_t)k * SDIM + (n - 64)];
        else             v = W_C[(size_t)k * SDIM + (n - 80)];
        Wcat[i] = f2b(v);
        return;
    }
    blk -= 768;
    {
        const int i = blk * 256 + threadIdx.x;
        A2[i] = -__expf(A_log[i]) * 1.44269504088896340736f;
    }
}

// ====== 256xBN MFMA GEMM, 16 waves (4x4), BK=64, T2 swizzle, dbuf ======
// + bijective XCD blockIdx swizzle (all grids here are %8 == 0)
#define MEPI_SPLIT_SILU 0
#define MEPI_OUT        1
#define MEPI_SP         2

template<int BN>
static __device__ __forceinline__
void stage256(const u16* __restrict__ A, const u16* __restrict__ Bt,
              u16 (*seg)[8192], int brow, int bcol, int K, int k0,
              int srow, int scol, int tid) {
    #pragma unroll
    for (int h = 0; h < 2; ++h) {
        const u16* sa = A + (size_t)(brow + h * 128 + srow) * K + k0 + scol;
        __builtin_amdgcn_global_load_lds(
            (const __attribute__((address_space(1))) void*)sa,
            (__attribute__((address_space(3))) void*)&seg[h][tid * 8], 16, 0, 0);
    }
    #pragma unroll
    for (int h = 0; h < BN / 128; ++h) {
        const u16* sb = Bt + (size_t)(bcol + h * 128 + srow) * K + k0 + scol;
        __builtin_amdgcn_global_load_lds(
            (const __attribute__((address_space(1))) void*)sb,
            (__attribute__((address_space(3))) void*)&seg[2 + h][tid * 8], 16, 0, 0);
    }
}

template<int BN, int EPI>
__global__ __launch_bounds__(1024)
void mgemm256(const u16* __restrict__ A, const u16* __restrict__ Bt,
              const float* __restrict__ bias, void* __restrict__ O0,
              void* __restrict__ O1, const float* __restrict__ res,
              int N, int K) {
    constexpr int NSEG = 2 + BN / 128;
    constexpr int L    = NSEG;
    constexpr int NFRag = BN / 64;
    __shared__ u16 lds[2][NSEG][8192];
    const int tid  = threadIdx.x;
    const int lane = tid & 63, wid = tid >> 6;
    const int wm = wid >> 2, wn = wid & 3;
    const int r  = lane & 15, kh = lane >> 4;
    // bijective XCD swizzle (nwg % 8 == 0 for all launches of this kernel)
    const int nwg  = gridDim.x * gridDim.y;
    const int orig = blockIdx.y * gridDim.x + blockIdx.x;
    const int swz  = (orig & 7) * (nwg >> 3) + (orig >> 3);
    const int bx   = swz % gridDim.x, by = swz / gridDim.x;
    const int brow = by * 256, bcol = bx * BN;

    int srow, scol;
    {
        const int q = tid;
        const int sub = q >> 6, qi = q & 63;
        const int qis = qi ^ (((qi >> 5) & 1) << 1);
        srow = (sub >> 1) * 16 + (qi >> 2);
        scol = ((sub & 1) << 5) + (qis & 3) * 8;
    }
    const int swz_kh = kh ^ (((r >> 3) & 1) << 1);
    const int rbase  = r * 32 + swz_kh * 8;
    const int am = wm & 1;

    f32x4 acc[4][NFRag];
    #pragma unroll
    for (int i = 0; i < 4; ++i)
        #pragma unroll
        for (int n = 0; n < NFRag; ++n) acc[i][n] = (f32x4){0.f, 0.f, 0.f, 0.f};

    const int NT = K >> 6;
    stage256<BN>(A, Bt, lds[0], brow, bcol, K, 0, srow, scol, tid);
    if (NT > 1) {
        stage256<BN>(A, Bt, lds[1], brow, bcol, K, 64, srow, scol, tid);
        waitcnt_vm<L>();
    } else {
        waitcnt_vm<0>();
    }
    __builtin_amdgcn_s_barrier();
    asm volatile("" ::: "memory");

    for (int kt = 0; kt < NT; ++kt) {
        const u16* segA = lds[kt & 1][wm >> 1];
        #pragma unroll
        for (int kk = 0; kk < 2; ++kk) {
            bf16x8 a[4], b[NFRag];
            #pragma unroll
            for (int mf = 0; mf < 4; ++mf)
                a[mf] = *(const bf16x8*)&segA[((am * 4 + mf) * 2 + kk) * 512 + rbase];
            #pragma unroll
            for (int nf = 0; nf < NFRag; ++nf) {
                const int nb = wn * NFRag + nf;
                const u16* segB = lds[kt & 1][2 + (nb >> 3)];
                b[nf] = *(const bf16x8*)&segB[(((nb & 7)) * 2 + kk) * 512 + rbase];
            }
            __builtin_amdgcn_s_setprio(1);
            #pragma unroll
            for (int mf = 0; mf < 4; ++mf)
                #pragma unroll
                for (int nf = 0; nf < NFRag; ++nf)
                    acc[mf][nf] = __builtin_amdgcn_mfma_f32_16x16x32_bf16(a[mf], b[nf], acc[mf][nf], 0, 0, 0);
            __builtin_amdgcn_s_setprio(0);
        }
        __builtin_amdgcn_s_barrier(); asm volatile("" ::: "memory");
        if (kt + 2 < NT) {
            stage256<BN>(A, Bt, lds[kt & 1], brow, bcol, K, (kt + 2) * 64, srow, scol, tid);
            waitcnt_vm<L>();
        } else {
            waitcnt_vm<0>();
        }
        __builtin_amdgcn_s_barrier(); asm volatile("" ::: "memory");
    }

    const int orow = brow + wm * 64 + kh * 4;
    const int ocol = bcol + wn * (BN / 4) + r;
    if constexpr (EPI == MEPI_SPLIT_SILU) {
        u16* dst; int cb;
        if (bcol < EXPN) { dst = (u16*)O0; cb = ocol; }
        else             { dst = (u16*)O1; cb = ocol - EXPN; }
        #pragma unroll
        for (int Mf = 0; Mf < 4; ++Mf)
            #pragma unroll
            for (int Nf = 0; Nf < NFRag; ++Nf)
                #pragma unroll
                for (int j = 0; j < 4; ++j) {
                    const int row = orow + Mf * 16 + j;
                    const int col = ocol + Nf * 16;
                    float v = acc[Mf][Nf][j] + bias[col];
                    dst[(size_t)row * EXPN + cb + Nf * 16] = f2b(fsilu(v));
                }
    } else if constexpr (EPI == MEPI_SP) {
        u16* o = (u16*)O0;
        #pragma unroll
        for (int Mf = 0; Mf < 4; ++Mf)
            #pragma unroll
            for (int Nf = 0; Nf < NFRag; ++Nf)
                #pragma unroll
                for (int j = 0; j < 4; ++j) {
                    const int row = orow + Mf * 16 + j;
                    const int col = ocol + Nf * 16;
                    float v = acc[Mf][Nf][j] + bias[col];
                    float sp = (v > 20.f) ? v
                             : 0.69314718056f * __builtin_amdgcn_logf(
                                   1.f + fexp2(1.44269504089f * v));
                    o[(size_t)row * N + col] = f2b(sp);
                }
    } else {
        float* o = (float*)O0;
        #pragma unroll
        for (int Mf = 0; Mf < 4; ++Mf)
            #pragma unroll
            for (int Nf = 0; Nf < NFRag; ++Nf)
                #pragma unroll
                for (int j = 0; j < 4; ++j) {
                    const int row = orow + Mf * 16 + j;
                    const int col = ocol + Nf * 16;
                    o[(size_t)row * N + col] = acc[Mf][Nf][j] + bias[col] + res[(size_t)row * N + col];
                }
    }
}

// -- fused split-K projection + last-block reduction: [t1|Bm|Cm] = u @ Wcat^T --
// grid (KSPL, MMN/128). Each block writes its partial; the last block per
// row-group (device-scope counter) reduces all KSPL partials in fixed order.
__global__ __launch_bounds__(256)
void k_proj(const u16* __restrict__ A, const u16* __restrict__ Wcat,
            float* __restrict__ Ppart, unsigned int* __restrict__ cnt,
            const float* __restrict__ b_del, const float* __restrict__ b_B,
            const float* __restrict__ b_C,
            u16* __restrict__ t1b, float* __restrict__ Bm,
            float* __restrict__ Cm) {
    __shared__ u16 As[128 * 32];
    __shared__ u16 Bs[96 * 32];
    const int tid  = threadIdx.x;
    const int wave = tid >> 6, lane = tid & 63;
    const int brow = blockIdx.y * 128;
    const int ks   = blockIdx.x;
    const int r = lane & 15, kh = lane >> 4;

    f32x4 acc[2][6];
    #pragma unroll
    for (int m = 0; m < 2; m++)
        #pragma unroll
        for (int n = 0; n < 6; n++) acc[m][n] = (f32x4){0.f, 0.f, 0.f, 0.f};

    const u16* ga0 = A + (size_t)(brow +      (tid >> 2)) * EXPN + ks * KCH + (tid & 3) * 8;
    const u16* ga1 = A + (size_t)(brow + 64 + (tid >> 2)) * EXPN + ks * KCH + (tid & 3) * 8;
    const u16* gb0 = Wcat + (size_t)(tid >> 2) * EXPN + ks * KCH + (tid & 3) * 8;
    const u16* gb1 = Wcat + (size_t)(64 + (tid >> 2)) * EXPN + ks * KCH + (tid & 3) * 8;
    u16* lA0 = As + (wave * 64) * 8;
    u16* lA1 = As + (256 + wave * 64) * 8;
    u16* lB0 = Bs + (wave * 64) * 8;
    u16* lB1 = Bs + (256 + wave * 64) * 8;

    for (int k0 = 0; k0 < KCH; k0 += 32) {
        __syncthreads();
        __builtin_amdgcn_global_load_lds((const __attribute__((address_space(1))) void*)(ga0 + k0),
                                         (__attribute__((address_space(3))) void*)lA0, 16, 0, 0);
        __builtin_amdgcn_global_load_lds((const __attribute__((address_space(1))) void*)(ga1 + k0),
                                         (__attribute__((address_space(3))) void*)lA1, 16, 0, 0);
        __builtin_amdgcn_global_load_lds((const __attribute__((address_space(1))) void*)(gb0 + k0),
                                         (__attribute__((address_space(3))) void*)lB0, 16, 0, 0);
        if (tid < 128)
            __builtin_amdgcn_global_load_lds((const __attribute__((address_space(1))) void*)(gb1 + k0),
                                             (__attribute__((address_space(3))) void*)lB1, 16, 0, 0);
        __syncthreads();
        bf16x8 af[2], bfr[6];
        #pragma unroll
        for (int mf = 0; mf < 2; ++mf)
            af[mf] = *(const bf16x8*)(As + ((wave * 32 + mf * 16 + r) * 32 + kh * 8));
        #pragma unroll
        for (int nf = 0; nf < 6; ++nf)
            bfr[nf] = *(const bf16x8*)(Bs + ((nf * 16 + r) * 32 + kh * 8));
        #pragma unroll
        for (int mf = 0; mf < 2; ++mf)
            #pragma unroll
            for (int nf = 0; nf < 6; ++nf)
                acc[mf][nf] = __builtin_amdgcn_mfma_f32_16x16x32_bf16(af[mf], bfr[nf], acc[mf][nf], 0, 0, 0);
    }
    const int orow = brow + wave * 32 + kh * 4;
    #pragma unroll
    for (int mf = 0; mf < 2; ++mf)
        #pragma unroll
        for (int nf = 0; nf < 6; ++nf)
            #pragma unroll
            for (int j = 0; j < 4; ++j)
                Ppart[((size_t)ks * MMN + orow + mf * 16 + j) * 96 + nf * 16 + r] = acc[mf][nf][j];

    // ---- last-block-per-row-group reduction (deterministic: fixed ks order)
    __threadfence();
    __syncthreads();
    __shared__ unsigned int last;
    if (tid == 0) last = atomicAdd(&cnt[blockIdx.y], 1u);
    __syncthreads();
    if (last != KSPL - 1) return;
    __threadfence();
    for (int it = tid; it < 128 * 96; it += 256) {
        const int row = brow + it / 96;
        const int col = it % 96;
        float s = 0.f;
        #pragma unroll
        for (int k = 0; k < KSPL; ++k)
            s += Ppart[((size_t)k * MMN + row) * 96 + col];
        if (col < 64)      t1b[(size_t)row * DTRN + col] = f2b(s + b_del[col]);
        else if (col < 80) Bm[(size_t)row * SDIM + col - 64] = s + b_B[col - 64];
        else               Cm[(size_t)row * SDIM + col - 80] = s + b_C[col - 80];
    }
}

// -------- chunked selective scan; state bf16 [b][c][e][s]; d-prefetched --------
__global__ __launch_bounds__(256)
void k_scan1(const u16* __restrict__ ub, const u16* __restrict__ db,
             const float* __restrict__ Bm, const float* __restrict__ A2,
             u16* __restrict__ hend, u16* __restrict__ Pp) {
    const int e = blockIdx.x * 256 + threadIdx.x;
    const int c = blockIdx.y, b = blockIdx.z;
    f32x2v a2p[8], hp[8];
    {
        const float4* ap = (const float4*)(A2 + (size_t)e * SDIM);
        #pragma unroll
        for (int q = 0; q < 4; ++q) {
            float4 v = ap[q];
            a2p[2*q]   = (f32x2v){v.x, v.y};
            a2p[2*q+1] = (f32x2v){v.z, v.w};
        }
    }
    #pragma unroll
    for (int i = 0; i < 8; ++i) hp[i] = (f32x2v){0.f, 0.f};
    float sumd = 0.f;
    const int t0 = c * CLEN;
    size_t rb = ((size_t)b * TTN + t0) * EXPN + e;
    size_t bb_ = ((size_t)b * TTN + t0) * SDIM;
    float dC = b2f(db[rb]), uC = b2f(ub[rb]);
    for (int tt = 0; tt < CLEN; ++tt) {
        const float dN = b2f(db[rb + EXPN]);
        const float uN = b2f(ub[rb + EXPN]);
        const float4* bp = (const float4*)(Bm + bb_);
        f32x2v bvp[8];
        #pragma unroll
        for (int q = 0; q < 4; ++q) {
            float4 v = bp[q];
            bvp[2*q]   = (f32x2v){v.x, v.y};
            bvp[2*q+1] = (f32x2v){v.z, v.w};
        }
        const float du = dC * uC;
        sumd += dC;
        #pragma unroll
        for (int i = 0; i < 8; ++i) {
            f32x2v arg = a2p[i] * dC;
            f32x2v ad; ad.x = fexp2(arg.x); ad.y = fexp2(arg.y);
            hp[i] = ad * hp[i] + bvp[i] * du;
        }
        dC = dN; uC = uN;
        rb += EXPN; bb_ += SDIM;
    }
    const size_t base = ((size_t)((b * NCHUNK + c)) * EXPN + e) * 16;
    union { u16 s[16]; uint4 v[2]; } he, pv;
    #pragma unroll
    for (int i = 0; i < 8; ++i) {
        he.s[2*i]   = f2b(hp[i].x);
        he.s[2*i+1] = f2b(hp[i].y);
        pv.s[2*i]   = f2b(fexp2(a2p[i].x * sumd));
        pv.s[2*i+1] = f2b(fexp2(a2p[i].y * sumd));
    }
    *(uint4*)(hend + base)     = he.v[0];
    *(uint4*)(hend + base + 8) = he.v[1];
    *(uint4*)(Pp + base)       = pv.v[0];
    *(uint4*)(Pp + base + 8)   = pv.v[1];
}

__global__ __launch_bounds__(256)
void k_fix(const u16* __restrict__ hend, const u16* __restrict__ Pp,
           u16* __restrict__ hinit) {
    const int i = blockIdx.x * 256 + threadIdx.x;     // over E*S = 32768
    const int b = blockIdx.y;
    float hi = 0.f;
    size_t idx = (size_t)b * NCHUNK * (EXPN * 16) + i;
    u16 pC = Pp[idx], hC = hend[idx];
    for (int cc = 0; cc < NCHUNK; ++cc) {
        const size_t idx2 = idx + EXPN * 16;
        u16 pN = 0, hN = 0;
        if (cc + 1 < NCHUNK) { pN = Pp[idx2]; hN = hend[idx2]; }
        hinit[idx] = f2b(hi);
        hi = fmaf(b2f(pC), hi, b2f(hC));
        pC = pN; hC = hN; idx = idx2;
    }
}

__global__ __launch_bounds__(256)
void k_scan2(const u16* __restrict__ ub, const u16* __restrict__ db,
             const u16* __restrict__ sgb, const float* __restrict__ Bm,
             const float* __restrict__ Cm, const float* __restrict__ A2,
             const u16* __restrict__ hinit, const float* __restrict__ Dp,
             u16* __restrict__ yb) {
    const int e = blockIdx.x * 256 + threadIdx.x;
    const int c = blockIdx.y, b = blockIdx.z;
    f32x2v a2p[8], hp[8];
    {
        const float4* ap = (const float4*)(A2 + (size_t)e * SDIM);
        #pragma unroll
        for (int q = 0; q < 4; ++q) {
            float4 v = ap[q];
            a2p[2*q]   = (f32x2v){v.x, v.y};
            a2p[2*q+1] = (f32x2v){v.z, v.w};
        }
    }
    {
        const size_t base = ((size_t)((b * NCHUNK + c)) * EXPN + e) * 16;
        union { u16 s[16]; uint4 v[2]; } hi;
        hi.v[0] = *(const uint4*)(hinit + base);
        hi.v[1] = *(const uint4*)(hinit + base + 8);
        #pragma unroll
        for (int i = 0; i < 8; ++i)
            hp[i] = (f32x2v){b2f(hi.s[2*i]), b2f(hi.s[2*i+1])};
    }
    const float dpe = Dp[e];
    const int t0 = c * CLEN;
    size_t rb = ((size_t)b * TTN + t0) * EXPN + e;
    size_t bb_ = ((size_t)b * TTN + t0) * SDIM;
    float dC = b2f(db[rb]), uC = b2f(ub[rb]), gC = b2f(sgb[rb]);
    for (int tt = 0; tt < CLEN; ++tt) {
        const float dN = b2f(db[rb + EXPN]);
        const float uN = b2f(ub[rb + EXPN]);
        const float gN = b2f(sgb[rb + EXPN]);
        const float4* bp = (const float4*)(Bm + bb_);
        const float4* cp = (const float4*)(Cm + bb_);
        f32x2v bvp[8], cvp[8];
        #pragma unroll
        for (int q = 0; q < 4; ++q) {
            float4 v = bp[q];
            bvp[2*q]   = (f32x2v){v.x, v.y};
            bvp[2*q+1] = (f32x2v){v.z, v.w};
            float4 w = cp[q];
            cvp[2*q]   = (f32x2v){w.x, w.y};
            cvp[2*q+1] = (f32x2v){w.z, w.w};
        }
        const float du = dC * uC;
        f32x2v ytp = (f32x2v){0.f, 0.f};
        #pragma unroll
        for (int i = 0; i < 8; ++i) {
            f32x2v arg = a2p[i] * dC;
            f32x2v ad; ad.x = fexp2(arg.x); ad.y = fexp2(arg.y);
            hp[i] = ad * hp[i] + bvp[i] * du;
            ytp = ytp + cvp[i] * hp[i];
        }
        yb[rb] = f2b(fmaf(uC, dpe, ytp.x + ytp.y) * gC);
        dC = dN; uC = uN; gC = gN;
        rb += EXPN; bb_ += SDIM;
    }
}

// ---------------- launch ----------------
extern "C" void kernel_launch(void* const* d_in, const int* in_sizes, int n_in,
                              void* d_out, int out_size, void* d_ws, size_t ws_size,
                              hipStream_t stream) {
    const float* x     = (const float*)d_in[0];
    const float* ln_g  = (const float*)d_in[1];
    const float* ln_b  = (const float*)d_in[2];
    const float* W_in  = (const float*)d_in[3];
    const float* b_in  = (const float*)d_in[4];
    const float* W_del = (const float*)d_in[5];
    const float* b_del = (const float*)d_in[6];
    const float* W_dt  = (const float*)d_in[7];
    const float* b_dt  = (const float*)d_in[8];
    const float* W_B   = (const float*)d_in[9];
    const float* b_B   = (const float*)d_in[10];
    const float* W_C   = (const float*)d_in[11];
    const float* b_C   = (const float*)d_in[12];
    const float* A_log = (const float*)d_in[13];
    const float* Dp    = (const float*)d_in[14];
    const float* W_out = (const float*)d_in[15];
    const float* b_out = (const float*)d_in[16];
    float* out = (float*)d_out;

    char* p = (char*)d_ws;
    auto alloc = [&](size_t bytes) {
        char* r = p; p += (bytes + 255) & ~(size_t)255; return (void*)r;
    };
    u16* xn   = (u16*)alloc((size_t)MMN * HIDN * 2);
    u16* u    = (u16*)alloc((size_t)MMN * EXPN * 2);
    u16* sg   = (u16*)alloc((size_t)MMN * EXPN * 2);
    u16* dl   = (u16*)alloc((size_t)MMN * EXPN * 2);
    u16* y    = (u16*)alloc((size_t)MMN * EXPN * 2);
    u16* t1b  = (u16*)alloc((size_t)MMN * DTRN * 2);
    float* Bm = (float*)alloc((size_t)MMN * SDIM * 4);
    float* Cm = (float*)alloc((size_t)MMN * SDIM * 4);
    float* A2 = (float*)alloc((size_t)EXPN * SDIM * 4);
    u16* Wt_in  = (u16*)alloc((size_t)(2 * EXPN) * HIDN * 2);
    u16* Wt_out = (u16*)alloc((size_t)HIDN * EXPN * 2);
    u16* Wcat   = (u16*)alloc((size_t)96 * EXPN * 2);
    u16* Wdt_t  = (u16*)alloc((size_t)EXPN * DTRN * 2);
    unsigned int* cnt = (unsigned int*)alloc(256 * sizeof(unsigned int));
    // state arrays bf16, [B][NCHUNK][E][S]; hend+Pp contiguous (16 MiB each)
    const size_t hsz = (size_t)BBN * NCHUNK * EXPN * SDIM * 2;
    u16* hend  = (u16*)alloc(hsz);
    u16* Pp    = (u16*)alloc(hsz);
    u16* hinit = (u16*)alloc(hsz);
    // Ppart (12.6 MB f32, KSPL=4) aliases hend (16 MiB): consumed inside
    // k_proj's reduction tail before scan1 writes.
    float* Ppart = (float*)hend;

    // zero the split-K completion counters (graph-capture-safe)
    hipMemsetAsync(cnt, 0, 256 * sizeof(unsigned int), stream);

    // fused prep: LN (8192 blocks) + transposes/cat/a2 (2464 blocks)
    k_prep<<<dim3(MMN + 1024 + 512 + 32 + 768 + 128), 256, 0, stream>>>(
        x, ln_g, ln_b, W_in, W_out, W_dt, W_del, W_B, W_C, A_log,
        xn, Wt_in, Wt_out, Wdt_t, Wcat, A2);

    // xp = xn @ W_in + b_in ; u = silu(left), sg = silu(right)  [256x256]
    mgemm256<256, MEPI_SPLIT_SILU><<<dim3(2 * EXPN / 256, MMN / 256), 1024, 0, stream>>>(
        xn, Wt_in, b_in, u, sg, nullptr, 2 * EXPN, HIDN);
    // fused projections + in-kernel reduction: [t1|Bm|Cm] = u @ [W_del|W_B|W_C]
    k_proj<<<dim3(KSPL, MMN / 128), 256, 0, stream>>>(
        u, Wcat, Ppart, cnt, b_del, b_B, b_C, t1b, Bm, Cm);
    // delta = softplus(t1 @ W_dt + b_dt)   [256x128, single K-tile]
    mgemm256<128, MEPI_SP><<<dim3(EXPN / 128, MMN / 256), 1024, 0, stream>>>(
        t1b, Wdt_t, b_dt, dl, nullptr, nullptr, EXPN, DTRN);
    // chunked selective scan (NCHUNK=64, CLEN=32)
    k_scan1<<<dim3(EXPN / 256, NCHUNK, BBN), 256, 0, stream>>>(u, dl, Bm, A2, hend, Pp);
    k_fix<<<dim3(EXPN * SDIM / 256, BBN), 256, 0, stream>>>(hend, Pp, hinit);
    k_scan2<<<dim3(EXPN / 256, NCHUNK, BBN), 256, 0, stream>>>(u, dl, sg, Bm, Cm, A2, hinit, Dp, y);
    // out = y @ W_out + b_out + x   [256x128]
    mgemm256<128, MEPI_OUT><<<dim3(HIDN / 128, MMN / 256), 1024, 0, stream>>>(
        y, Wt_out, b_out, out, nullptr, x, HIDN, EXPN);
}

// Round 13
// 278.821 us; speedup vs baseline: 1.2644x; 1.2644x over previous
//
#include <hip/hip_runtime.h>

#define HIDN 1024
#define EXPN 2048
#define SDIM 16
#define DTRN 64
#define BBN  4
#define TTN  2048
#define MMN  (BBN*TTN)        // 8192 rows
#define NCHUNK 64
#define CLEN (TTN/NCHUNK)     // 32
#define KSPL 4                // split-K chunks for k_proj
#define KCH  (EXPN/KSPL)      // 512

typedef unsigned short u16;
typedef __bf16 bf16x8 __attribute__((ext_vector_type(8)));
typedef float f32x4 __attribute__((ext_vector_type(4)));
typedef float f32x2v __attribute__((ext_vector_type(2)));

static __device__ __forceinline__ float b2f(u16 u) {
    union { unsigned int i; float f; } cv; cv.i = ((unsigned int)u) << 16; return cv.f;
}
static __device__ __forceinline__ u16 f2b(float f) {
    union { float f; unsigned int i; } cv; cv.f = f;
    unsigned int x = cv.i;
    return (u16)((x + 0x7fffu + ((x >> 16) & 1u)) >> 16);
}
static __device__ __forceinline__ float fexp2(float x) {
    return __builtin_amdgcn_exp2f(x);
}
static __device__ __forceinline__ float fsilu(float v) {
    return v / (1.f + fexp2(-1.44269504088896f * v));
}
template<int L> static __device__ __forceinline__ void waitcnt_vm() {
    if constexpr (L == 0) asm volatile("s_waitcnt vmcnt(0)" ::: "memory");
    else if constexpr (L == 3) asm volatile("s_waitcnt vmcnt(3)" ::: "memory");
    else if constexpr (L == 4) asm volatile("s_waitcnt vmcnt(4)" ::: "memory");
}

// ------- fused prep: LayerNorm + 3 transposes + cat + a2, ONE launch -------
static __device__ __forceinline__
void tr_tile(const float* __restrict__ W, u16* __restrict__ Wt,
             int K, int N, int bk, int bn, float (*t)[65]) {
    const int r0 = threadIdx.x >> 4, c0 = (threadIdx.x & 15) << 2;
    #pragma unroll
    for (int i = 0; i < 4; ++i) {
        float4 v = *(const float4*)(W + (size_t)(bk + r0 + i * 16) * N + bn + c0);
        t[r0 + i * 16][c0 + 0] = v.x; t[r0 + i * 16][c0 + 1] = v.y;
        t[r0 + i * 16][c0 + 2] = v.z; t[r0 + i * 16][c0 + 3] = v.w;
    }
    __syncthreads();
    #pragma unroll
    for (int i = 0; i < 4; ++i) {
        const int n = r0 + i * 16;
        ushort4 o;
        o.x = f2b(t[c0 + 0][n]); o.y = f2b(t[c0 + 1][n]);
        o.z = f2b(t[c0 + 2][n]); o.w = f2b(t[c0 + 3][n]);
        *(ushort4*)(Wt + (size_t)(bn + n) * K + bk + c0) = o;
    }
}

__global__ __launch_bounds__(256)
void k_prep(const float* __restrict__ x, const float* __restrict__ ln_g,
            const float* __restrict__ ln_b,
            const float* __restrict__ W_in, const float* __restrict__ W_out,
            const float* __restrict__ W_dt, const float* __restrict__ W_del,
            const float* __restrict__ W_B, const float* __restrict__ W_C,
            const float* __restrict__ A_log,
            u16* __restrict__ xn,
            u16* __restrict__ Wt_in, u16* __restrict__ Wt_out,
            u16* __restrict__ Wdt_t, u16* __restrict__ Wcat,
            float* __restrict__ A2) {
    __shared__ float t[64][65];
    __shared__ float as[4], bs[4];
    int blk = blockIdx.x;
    if (blk < MMN) {                         // LayerNorm rows
        const int row = blk, tid = threadIdx.x;
        const float4 xv = ((const float4*)(x + (size_t)row * HIDN))[tid];
        float s  = xv.x + xv.y + xv.z + xv.w;
        float ss = fmaf(xv.x, xv.x, fmaf(xv.y, xv.y, fmaf(xv.z, xv.z, xv.w * xv.w)));
        #pragma unroll
        for (int o = 32; o > 0; o >>= 1) { s += __shfl_down(s, o); ss += __shfl_down(ss, o); }
        const int wid = tid >> 6, lane = tid & 63;
        if (lane == 0) { as[wid] = s; bs[wid] = ss; }
        __syncthreads();
        const float S  = as[0] + as[1] + as[2] + as[3];
        const float SS = bs[0] + bs[1] + bs[2] + bs[3];
        const float mean = S * (1.f / HIDN);
        const float var  = SS * (1.f / HIDN) - mean * mean;
        const float r = rsqrtf(var + 1e-5f);
        const float4 gv = ((const float4*)ln_g)[tid];
        const float4 bv = ((const float4*)ln_b)[tid];
        ushort4 o;
        o.x = f2b((xv.x - mean) * r * gv.x + bv.x);
        o.y = f2b((xv.y - mean) * r * gv.y + bv.y);
        o.z = f2b((xv.z - mean) * r * gv.z + bv.z);
        o.w = f2b((xv.w - mean) * r * gv.w + bv.w);
        ((ushort4*)(xn + (size_t)row * HIDN))[tid] = o;
        return;
    }
    blk -= MMN;
    if (blk < 1024) {
        tr_tile(W_in, Wt_in, HIDN, 2 * EXPN, (blk >> 6) << 6, (blk & 63) << 6, t);
        return;
    }
    blk -= 1024;
    if (blk < 512) {
        tr_tile(W_out, Wt_out, EXPN, HIDN, (blk >> 4) << 6, (blk & 15) << 6, t);
        return;
    }
    blk -= 512;
    if (blk < 32) {
        tr_tile(W_dt, Wdt_t, DTRN, EXPN, 0, blk << 6, t);
        return;
    }
    blk -= 32;
    if (blk < 768) {
        const int i = blk * 256 + threadIdx.x;
        const int n = i >> 11, k = i & 2047;
        float v;
        if (n < 64)      v = W_del[(size_t)k * DTRN + n];
        else if (n < 80) v = W_B[(size_t)k * SDIM + (n - 64)];
        else             v = W_C[(size_t)k * SDIM + (n - 80)];
        Wcat[i] = f2b(v);
        return;
    }
    blk -= 768;
    {
        const int i = blk * 256 + threadIdx.x;
        A2[i] = -__expf(A_log[i]) * 1.44269504088896340736f;
    }
}

// ====== 256xBN MFMA GEMM, 16 waves (4x4), BK=64, T2 swizzle, dbuf ======
// + bijective XCD blockIdx swizzle (all grids here are %8 == 0)
#define MEPI_SPLIT_SILU 0
#define MEPI_OUT        1
#define MEPI_SP         2

template<int BN>
static __device__ __forceinline__
void stage256(const u16* __restrict__ A, const u16* __restrict__ Bt,
              u16 (*seg)[8192], int brow, int bcol, int K, int k0,
              int srow, int scol, int tid) {
    #pragma unroll
    for (int h = 0; h < 2; ++h) {
        const u16* sa = A + (size_t)(brow + h * 128 + srow) * K + k0 + scol;
        __builtin_amdgcn_global_load_lds(
            (const __attribute__((address_space(1))) void*)sa,
            (__attribute__((address_space(3))) void*)&seg[h][tid * 8], 16, 0, 0);
    }
    #pragma unroll
    for (int h = 0; h < BN / 128; ++h) {
        const u16* sb = Bt + (size_t)(bcol + h * 128 + srow) * K + k0 + scol;
        __builtin_amdgcn_global_load_lds(
            (const __attribute__((address_space(1))) void*)sb,
            (__attribute__((address_space(3))) void*)&seg[2 + h][tid * 8], 16, 0, 0);
    }
}

template<int BN, int EPI>
__global__ __launch_bounds__(1024)
void mgemm256(const u16* __restrict__ A, const u16* __restrict__ Bt,
              const float* __restrict__ bias, void* __restrict__ O0,
              void* __restrict__ O1, const float* __restrict__ res,
              int N, int K) {
    constexpr int NSEG = 2 + BN / 128;
    constexpr int L    = NSEG;
    constexpr int NFRag = BN / 64;
    __shared__ u16 lds[2][NSEG][8192];
    const int tid  = threadIdx.x;
    const int lane = tid & 63, wid = tid >> 6;
    const int wm = wid >> 2, wn = wid & 3;
    const int r  = lane & 15, kh = lane >> 4;
    // bijective XCD swizzle (nwg % 8 == 0 for all launches of this kernel)
    const int nwg  = gridDim.x * gridDim.y;
    const int orig = blockIdx.y * gridDim.x + blockIdx.x;
    const int swz  = (orig & 7) * (nwg >> 3) + (orig >> 3);
    const int bx   = swz % gridDim.x, by = swz / gridDim.x;
    const int brow = by * 256, bcol = bx * BN;

    int srow, scol;
    {
        const int q = tid;
        const int sub = q >> 6, qi = q & 63;
        const int qis = qi ^ (((qi >> 5) & 1) << 1);
        srow = (sub >> 1) * 16 + (qi >> 2);
        scol = ((sub & 1) << 5) + (qis & 3) * 8;
    }
    const int swz_kh = kh ^ (((r >> 3) & 1) << 1);
    const int rbase  = r * 32 + swz_kh * 8;
    const int am = wm & 1;

    f32x4 acc[4][NFRag];
    #pragma unroll
    for (int i = 0; i < 4; ++i)
        #pragma unroll
        for (int n = 0; n < NFRag; ++n) acc[i][n] = (f32x4){0.f, 0.f, 0.f, 0.f};

    const int NT = K >> 6;
    stage256<BN>(A, Bt, lds[0], brow, bcol, K, 0, srow, scol, tid);
    if (NT > 1) {
        stage256<BN>(A, Bt, lds[1], brow, bcol, K, 64, srow, scol, tid);
        waitcnt_vm<L>();
    } else {
        waitcnt_vm<0>();
    }
    __builtin_amdgcn_s_barrier();
    asm volatile("" ::: "memory");

    for (int kt = 0; kt < NT; ++kt) {
        const u16* segA = lds[kt & 1][wm >> 1];
        #pragma unroll
        for (int kk = 0; kk < 2; ++kk) {
            bf16x8 a[4], b[NFRag];
            #pragma unroll
            for (int mf = 0; mf < 4; ++mf)
                a[mf] = *(const bf16x8*)&segA[((am * 4 + mf) * 2 + kk) * 512 + rbase];
            #pragma unroll
            for (int nf = 0; nf < NFRag; ++nf) {
                const int nb = wn * NFRag + nf;
                const u16* segB = lds[kt & 1][2 + (nb >> 3)];
                b[nf] = *(const bf16x8*)&segB[(((nb & 7)) * 2 + kk) * 512 + rbase];
            }
            __builtin_amdgcn_s_setprio(1);
            #pragma unroll
            for (int mf = 0; mf < 4; ++mf)
                #pragma unroll
                for (int nf = 0; nf < NFRag; ++nf)
                    acc[mf][nf] = __builtin_amdgcn_mfma_f32_16x16x32_bf16(a[mf], b[nf], acc[mf][nf], 0, 0, 0);
            __builtin_amdgcn_s_setprio(0);
        }
        __builtin_amdgcn_s_barrier(); asm volatile("" ::: "memory");
        if (kt + 2 < NT) {
            stage256<BN>(A, Bt, lds[kt & 1], brow, bcol, K, (kt + 2) * 64, srow, scol, tid);
            waitcnt_vm<L>();
        } else {
            waitcnt_vm<0>();
        }
        __builtin_amdgcn_s_barrier(); asm volatile("" ::: "memory");
    }

    const int orow = brow + wm * 64 + kh * 4;
    const int ocol = bcol + wn * (BN / 4) + r;
    if constexpr (EPI == MEPI_SPLIT_SILU) {
        u16* dst; int cb;
        if (bcol < EXPN) { dst = (u16*)O0; cb = ocol; }
        else             { dst = (u16*)O1; cb = ocol - EXPN; }
        #pragma unroll
        for (int Mf = 0; Mf < 4; ++Mf)
            #pragma unroll
            for (int Nf = 0; Nf < NFRag; ++Nf)
                #pragma unroll
                for (int j = 0; j < 4; ++j) {
                    const int row = orow + Mf * 16 + j;
                    const int col = ocol + Nf * 16;
                    float v = acc[Mf][Nf][j] + bias[col];
                    dst[(size_t)row * EXPN + cb + Nf * 16] = f2b(fsilu(v));
                }
    } else if constexpr (EPI == MEPI_SP) {
        u16* o = (u16*)O0;
        #pragma unroll
        for (int Mf = 0; Mf < 4; ++Mf)
            #pragma unroll
            for (int Nf = 0; Nf < NFRag; ++Nf)
                #pragma unroll
                for (int j = 0; j < 4; ++j) {
                    const int row = orow + Mf * 16 + j;
                    const int col = ocol + Nf * 16;
                    float v = acc[Mf][Nf][j] + bias[col];
                    float sp = (v > 20.f) ? v
                             : 0.69314718056f * __builtin_amdgcn_logf(
                                   1.f + fexp2(1.44269504089f * v));
                    o[(size_t)row * N + col] = f2b(sp);
                }
    } else {
        float* o = (float*)O0;
        #pragma unroll
        for (int Mf = 0; Mf < 4; ++Mf)
            #pragma unroll
            for (int Nf = 0; Nf < NFRag; ++Nf)
                #pragma unroll
                for (int j = 0; j < 4; ++j) {
                    const int row = orow + Mf * 16 + j;
                    const int col = ocol + Nf * 16;
                    o[(size_t)row * N + col] = acc[Mf][Nf][j] + bias[col] + res[(size_t)row * N + col];
                }
    }
}

// -------- fused split-K projection: P = u @ Wcat^T (M x 96), KSPL=4 --------
__global__ __launch_bounds__(256)
void k_proj(const u16* __restrict__ A, const u16* __restrict__ Wcat,
            float* __restrict__ Ppart) {
    __shared__ u16 As[128 * 32];
    __shared__ u16 Bs[96 * 32];
    const int tid  = threadIdx.x;
    const int wave = tid >> 6, lane = tid & 63;
    const int brow = blockIdx.y * 128;
    const int ks   = blockIdx.x;
    const int r = lane & 15, kh = lane >> 4;

    f32x4 acc[2][6];
    #pragma unroll
    for (int m = 0; m < 2; m++)
        #pragma unroll
        for (int n = 0; n < 6; n++) acc[m][n] = (f32x4){0.f, 0.f, 0.f, 0.f};

    const u16* ga0 = A + (size_t)(brow +      (tid >> 2)) * EXPN + ks * KCH + (tid & 3) * 8;
    const u16* ga1 = A + (size_t)(brow + 64 + (tid >> 2)) * EXPN + ks * KCH + (tid & 3) * 8;
    const u16* gb0 = Wcat + (size_t)(tid >> 2) * EXPN + ks * KCH + (tid & 3) * 8;
    const u16* gb1 = Wcat + (size_t)(64 + (tid >> 2)) * EXPN + ks * KCH + (tid & 3) * 8;
    u16* lA0 = As + (wave * 64) * 8;
    u16* lA1 = As + (256 + wave * 64) * 8;
    u16* lB0 = Bs + (wave * 64) * 8;
    u16* lB1 = Bs + (256 + wave * 64) * 8;

    for (int k0 = 0; k0 < KCH; k0 += 32) {
        __syncthreads();
        __builtin_amdgcn_global_load_lds((const __attribute__((address_space(1))) void*)(ga0 + k0),
                                         (__attribute__((address_space(3))) void*)lA0, 16, 0, 0);
        __builtin_amdgcn_global_load_lds((const __attribute__((address_space(1))) void*)(ga1 + k0),
                                         (__attribute__((address_space(3))) void*)lA1, 16, 0, 0);
        __builtin_amdgcn_global_load_lds((const __attribute__((address_space(1))) void*)(gb0 + k0),
                                         (__attribute__((address_space(3))) void*)lB0, 16, 0, 0);
        if (tid < 128)
            __builtin_amdgcn_global_load_lds((const __attribute__((address_space(1))) void*)(gb1 + k0),
                                             (__attribute__((address_space(3))) void*)lB1, 16, 0, 0);
        __syncthreads();
        bf16x8 af[2], bfr[6];
        #pragma unroll
        for (int mf = 0; mf < 2; ++mf)
            af[mf] = *(const bf16x8*)(As + ((wave * 32 + mf * 16 + r) * 32 + kh * 8));
        #pragma unroll
        for (int nf = 0; nf < 6; ++nf)
            bfr[nf] = *(const bf16x8*)(Bs + ((nf * 16 + r) * 32 + kh * 8));
        #pragma unroll
        for (int mf = 0; mf < 2; ++mf)
            #pragma unroll
            for (int nf = 0; nf < 6; ++nf)
                acc[mf][nf] = __builtin_amdgcn_mfma_f32_16x16x32_bf16(af[mf], bfr[nf], acc[mf][nf], 0, 0, 0);
    }
    const int orow = brow + wave * 32 + kh * 4;
    #pragma unroll
    for (int mf = 0; mf < 2; ++mf)
        #pragma unroll
        for (int nf = 0; nf < 6; ++nf)
            #pragma unroll
            for (int j = 0; j < 4; ++j)
                Ppart[((size_t)ks * MMN + orow + mf * 16 + j) * 96 + nf * 16 + r] = acc[mf][nf][j];
}

// ---------------- reduce split-K partials -> t1 (bf16), Bm, Cm (f32) ----------------
__global__ __launch_bounds__(192)
void k_red(const float* __restrict__ Ppart, const float* __restrict__ b_del,
           const float* __restrict__ b_B, const float* __restrict__ b_C,
           u16* __restrict__ t1b, float* __restrict__ Bm, float* __restrict__ Cm) {
    const int tid = threadIdx.x;
    const int ri  = tid / 96, col = tid - ri * 96;
    const int row = blockIdx.x * 2 + ri;
    float s = 0.f;
    #pragma unroll
    for (int ks = 0; ks < KSPL; ++ks)
        s += Ppart[((size_t)ks * MMN + row) * 96 + col];
    if (col < 64)      t1b[(size_t)row * DTRN + col] = f2b(s + b_del[col]);
    else if (col < 80) Bm[(size_t)row * SDIM + col - 64] = s + b_B[col - 64];
    else               Cm[(size_t)row * SDIM + col - 80] = s + b_C[col - 80];
}

// -------- chunked selective scan; state bf16 [b][c][e][s]; d-prefetched --------
__global__ __launch_bounds__(256)
void k_scan1(const u16* __restrict__ ub, const u16* __restrict__ db,
             const float* __restrict__ Bm, const float* __restrict__ A2,
             u16* __restrict__ hend, u16* __restrict__ Pp) {
    const int e = blockIdx.x * 256 + threadIdx.x;
    const int c = blockIdx.y, b = blockIdx.z;
    f32x2v a2p[8], hp[8];
    {
        const float4* ap = (const float4*)(A2 + (size_t)e * SDIM);
        #pragma unroll
        for (int q = 0; q < 4; ++q) {
            float4 v = ap[q];
            a2p[2*q]   = (f32x2v){v.x, v.y};
            a2p[2*q+1] = (f32x2v){v.z, v.w};
        }
    }
    #pragma unroll
    for (int i = 0; i < 8; ++i) hp[i] = (f32x2v){0.f, 0.f};
    float sumd = 0.f;
    const int t0 = c * CLEN;
    size_t rb = ((size_t)b * TTN + t0) * EXPN + e;
    size_t bb_ = ((size_t)b * TTN + t0) * SDIM;
    float dC = b2f(db[rb]), uC = b2f(ub[rb]);
    for (int tt = 0; tt < CLEN; ++tt) {
        const float dN = b2f(db[rb + EXPN]);
        const float uN = b2f(ub[rb + EXPN]);
        const float4* bp = (const float4*)(Bm + bb_);
        f32x2v bvp[8];
        #pragma unroll
        for (int q = 0; q < 4; ++q) {
            float4 v = bp[q];
            bvp[2*q]   = (f32x2v){v.x, v.y};
            bvp[2*q+1] = (f32x2v){v.z, v.w};
        }
        const float du = dC * uC;
        sumd += dC;
        #pragma unroll
        for (int i = 0; i < 8; ++i) {
            f32x2v arg = a2p[i] * dC;
            f32x2v ad; ad.x = fexp2(arg.x); ad.y = fexp2(arg.y);
            hp[i] = ad * hp[i] + bvp[i] * du;
        }
        dC = dN; uC = uN;
        rb += EXPN; bb_ += SDIM;
    }
    const size_t base = ((size_t)((b * NCHUNK + c)) * EXPN + e) * 16;
    union { u16 s[16]; uint4 v[2]; } he, pv;
    #pragma unroll
    for (int i = 0; i < 8; ++i) {
        he.s[2*i]   = f2b(hp[i].x);
        he.s[2*i+1] = f2b(hp[i].y);
        pv.s[2*i]   = f2b(fexp2(a2p[i].x * sumd));
        pv.s[2*i+1] = f2b(fexp2(a2p[i].y * sumd));
    }
    *(uint4*)(hend + base)     = he.v[0];
    *(uint4*)(hend + base + 8) = he.v[1];
    *(uint4*)(Pp + base)       = pv.v[0];
    *(uint4*)(Pp + base + 8)   = pv.v[1];
}

__global__ __launch_bounds__(256)
void k_fix(const u16* __restrict__ hend, const u16* __restrict__ Pp,
           u16* __restrict__ hinit) {
    const int i = blockIdx.x * 256 + threadIdx.x;     // over E*S = 32768
    const int b = blockIdx.y;
    float hi = 0.f;
    size_t idx = (size_t)b * NCHUNK * (EXPN * 16) + i;
    u16 pC = Pp[idx], hC = hend[idx];
    for (int cc = 0; cc < NCHUNK; ++cc) {
        const size_t idx2 = idx + EXPN * 16;
        u16 pN = 0, hN = 0;
        if (cc + 1 < NCHUNK) { pN = Pp[idx2]; hN = hend[idx2]; }
        hinit[idx] = f2b(hi);
        hi = fmaf(b2f(pC), hi, b2f(hC));
        pC = pN; hC = hN; idx = idx2;
    }
}

__global__ __launch_bounds__(256)
void k_scan2(const u16* __restrict__ ub, const u16* __restrict__ db,
             const u16* __restrict__ sgb, const float* __restrict__ Bm,
             const float* __restrict__ Cm, const float* __restrict__ A2,
             const u16* __restrict__ hinit, const float* __restrict__ Dp,
             u16* __restrict__ yb) {
    const int e = blockIdx.x * 256 + threadIdx.x;
    const int c = blockIdx.y, b = blockIdx.z;
    f32x2v a2p[8], hp[8];
    {
        const float4* ap = (const float4*)(A2 + (size_t)e * SDIM);
        #pragma unroll
        for (int q = 0; q < 4; ++q) {
            float4 v = ap[q];
            a2p[2*q]   = (f32x2v){v.x, v.y};
            a2p[2*q+1] = (f32x2v){v.z, v.w};
        }
    }
    {
        const size_t base = ((size_t)((b * NCHUNK + c)) * EXPN + e) * 16;
        union { u16 s[16]; uint4 v[2]; } hi;
        hi.v[0] = *(const uint4*)(hinit + base);
        hi.v[1] = *(const uint4*)(hinit + base + 8);
        #pragma unroll
        for (int i = 0; i < 8; ++i)
            hp[i] = (f32x2v){b2f(hi.s[2*i]), b2f(hi.s[2*i+1])};
    }
    const float dpe = Dp[e];
    const int t0 = c * CLEN;
    size_t rb = ((size_t)b * TTN + t0) * EXPN + e;
    size_t bb_ = ((size_t)b * TTN + t0) * SDIM;
    float dC = b2f(db[rb]), uC = b2f(ub[rb]), gC = b2f(sgb[rb]);
    for (int tt = 0; tt < CLEN; ++tt) {
        const float dN = b2f(db[rb + EXPN]);
        const float uN = b2f(ub[rb + EXPN]);
        const float gN = b2f(sgb[rb + EXPN]);
        const float4* bp = (const float4*)(Bm + bb_);
        const float4* cp = (const float4*)(Cm + bb_);
        f32x2v bvp[8], cvp[8];
        #pragma unroll
        for (int q = 0; q < 4; ++q) {
            float4 v = bp[q];
            bvp[2*q]   = (f32x2v){v.x, v.y};
            bvp[2*q+1] = (f32x2v){v.z, v.w};
            float4 w = cp[q];
            cvp[2*q]   = (f32x2v){w.x, w.y};
            cvp[2*q+1] = (f32x2v){w.z, w.w};
        }
        const float du = dC * uC;
        f32x2v ytp = (f32x2v){0.f, 0.f};
        #pragma unroll
        for (int i = 0; i < 8; ++i) {
            f32x2v arg = a2p[i] * dC;
            f32x2v ad; ad.x = fexp2(arg.x); ad.y = fexp2(arg.y);
            hp[i] = ad * hp[i] + bvp[i] * du;
            ytp = ytp + cvp[i] * hp[i];
        }
        yb[rb] = f2b(fmaf(uC, dpe, ytp.x + ytp.y) * gC);
        dC = dN; uC = uN; gC = gN;
        rb += EXPN; bb_ += SDIM;
    }
}

// ---------------- launch ----------------
extern "C" void kernel_launch(void* const* d_in, const int* in_sizes, int n_in,
                              void* d_out, int out_size, void* d_ws, size_t ws_size,
                              hipStream_t stream) {
    const float* x     = (const float*)d_in[0];
    const float* ln_g  = (const float*)d_in[1];
    const float* ln_b  = (const float*)d_in[2];
    const float* W_in  = (const float*)d_in[3];
    const float* b_in  = (const float*)d_in[4];
    const float* W_del = (const float*)d_in[5];
    const float* b_del = (const float*)d_in[6];
    const float* W_dt  = (const float*)d_in[7];
    const float* b_dt  = (const float*)d_in[8];
    const float* W_B   = (const float*)d_in[9];
    const float* b_B   = (const float*)d_in[10];
    const float* W_C   = (const float*)d_in[11];
    const float* b_C   = (const float*)d_in[12];
    const float* A_log = (const float*)d_in[13];
    const float* Dp    = (const float*)d_in[14];
    const float* W_out = (const float*)d_in[15];
    const float* b_out = (const float*)d_in[16];
    float* out = (float*)d_out;

    char* p = (char*)d_ws;
    auto alloc = [&](size_t bytes) {
        char* r = p; p += (bytes + 255) & ~(size_t)255; return (void*)r;
    };
    u16* xn   = (u16*)alloc((size_t)MMN * HIDN * 2);
    u16* u    = (u16*)alloc((size_t)MMN * EXPN * 2);
    u16* sg   = (u16*)alloc((size_t)MMN * EXPN * 2);
    u16* dl   = (u16*)alloc((size_t)MMN * EXPN * 2);
    u16* y    = (u16*)alloc((size_t)MMN * EXPN * 2);
    u16* t1b  = (u16*)alloc((size_t)MMN * DTRN * 2);
    float* Bm = (float*)alloc((size_t)MMN * SDIM * 4);
    float* Cm = (float*)alloc((size_t)MMN * SDIM * 4);
    float* A2 = (float*)alloc((size_t)EXPN * SDIM * 4);
    u16* Wt_in  = (u16*)alloc((size_t)(2 * EXPN) * HIDN * 2);
    u16* Wt_out = (u16*)alloc((size_t)HIDN * EXPN * 2);
    u16* Wcat   = (u16*)alloc((size_t)96 * EXPN * 2);
    u16* Wdt_t  = (u16*)alloc((size_t)EXPN * DTRN * 2);
    // state arrays bf16, [B][NCHUNK][E][S]; hend+Pp contiguous (16 MiB each)
    const size_t hsz = (size_t)BBN * NCHUNK * EXPN * SDIM * 2;
    u16* hend  = (u16*)alloc(hsz);
    u16* Pp    = (u16*)alloc(hsz);
    u16* hinit = (u16*)alloc(hsz);
    // Ppart (12.6 MB f32, KSPL=4) aliases hend+Pp (32 MiB): consumed by k_red
    // before scan1 writes.
    float* Ppart = (float*)hend;

    // fused prep: LN (8192 blocks) + transposes/cat/a2 (2464 blocks)
    k_prep<<<dim3(MMN + 1024 + 512 + 32 + 768 + 128), 256, 0, stream>>>(
        x, ln_g, ln_b, W_in, W_out, W_dt, W_del, W_B, W_C, A_log,
        xn, Wt_in, Wt_out, Wdt_t, Wcat, A2);

    // xp = xn @ W_in + b_in ; u = silu(left), sg = silu(right)  [256x256]
    mgemm256<256, MEPI_SPLIT_SILU><<<dim3(2 * EXPN / 256, MMN / 256), 1024, 0, stream>>>(
        xn, Wt_in, b_in, u, sg, nullptr, 2 * EXPN, HIDN);
    // fused projections: [t1|Bm|Cm] = u @ [W_del|W_B|W_C]   [MFMA split-K=4]
    k_proj<<<dim3(KSPL, MMN / 128), 256, 0, stream>>>(u, Wcat, Ppart);
    k_red<<<dim3(MMN / 2), 192, 0, stream>>>(Ppart, b_del, b_B, b_C, t1b, Bm, Cm);
    // delta = softplus(t1 @ W_dt + b_dt)   [256x128, single K-tile]
    mgemm256<128, MEPI_SP><<<dim3(EXPN / 128, MMN / 256), 1024, 0, stream>>>(
        t1b, Wdt_t, b_dt, dl, nullptr, nullptr, EXPN, DTRN);
    // chunked selective scan (NCHUNK=64, CLEN=32)
    k_scan1<<<dim3(EXPN / 256, NCHUNK, BBN), 256, 0, stream>>>(u, dl, Bm, A2, hend, Pp);
    k_fix<<<dim3(EXPN * SDIM / 256, BBN), 256, 0, stream>>>(hend, Pp, hinit);
    k_scan2<<<dim3(EXPN / 256, NCHUNK, BBN), 256, 0, stream>>>(u, dl, sg, Bm, Cm, A2, hinit, Dp, y);
    // out = y @ W_out + b_out + x   [256x128]
    mgemm256<128, MEPI_OUT><<<dim3(HIDN / 128, MMN / 256), 1024, 0, stream>>>(
        y, Wt_out, b_out, out, nullptr, x, HIDN, EXPN);
}